// Round 4
// baseline (409.820 us; speedup 1.0000x reference)
//
#include <hip/hip_runtime.h>

#define NB 64
#define NDIM 512
#define NNE (NDIM * NDIM)      // 262144
#define NR 40
#define NL 20
#define SUBS 16                // blocks per batch
#define IT 16                  // float4 iters per thread (64 elems)

// ws layout (floats):
#define K1OFF 0
#define K1STRIDE 16
#define K2OFF (NB * SUBS * K1STRIDE)           // 16384
#define K3OFF (K2OFF + NB * SUBS)              // 17408
#define K3STRIDE 48
#define RT_OFF (K3OFF + NB * SUBS * K3STRIDE)  // 66560
#define FLAG_OFF (RT_OFF + NB * 4)             // 66816  (~261 KB total)

__global__ void detect_kernel(const unsigned int* __restrict__ hp, int* __restrict__ flag) {
    unsigned int v = hp[threadIdx.x];
    unsigned long long m = __ballot(v > 1u);
    if (threadIdx.x == 0) *flag = (m != 0ull) ? 1 : 0;
}

// ---------------- K1: demand+transit+ntr+has_path scalar sums ----------------
template<bool BYTE>
__device__ __forceinline__ void k1loop(const float* __restrict__ pd,
                                       const float* __restrict__ pt,
                                       const int* __restrict__ pn,
                                       const void* __restrict__ ph,
                                       float acc[9])
{
#pragma unroll 4
    for (int it = 0; it < IT; ++it) {
        const int o = it * 1024;
        const float4 dem = *(const float4*)(pd + o);
        const float4 tt  = *(const float4*)(pt + o);
        const int4   nt  = *(const int4*)(pn + o);
        int h[4];
        if (BYTE) {
            const uchar4 hb = *(const uchar4*)((const unsigned char*)ph + o);
            h[0] = hb.x; h[1] = hb.y; h[2] = hb.z; h[3] = hb.w;
        } else {
            const int4 hw = *(const int4*)((const int*)ph + o);
            h[0] = hw.x; h[1] = hw.y; h[2] = hw.z; h[3] = hw.w;
        }
        const float dm[4] = {dem.x, dem.y, dem.z, dem.w};
        const float tv[4] = {tt.x, tt.y, tt.z, tt.w};
        const int   nv[4] = {nt.x, nt.y, nt.z, nt.w};
#pragma unroll
        for (int e = 0; e < 4; ++e) {
            const float d = dm[e];
            const bool np_ = (h[e] == 0);
            const int nte = np_ ? 3 : nv[e];
            acc[0] += (nte == 0) ? d : 0.0f;
            acc[1] += (nte == 1) ? d : 0.0f;
            acc[2] += (nte == 2) ? d : 0.0f;
            acc[3] += (nte > 2) ? d : 0.0f;
            acc[4] += np_ ? 0.0f : d * tv[e];
            acc[5] += np_ ? d : 0.0f;
            acc[6] += d;
            const bool pos = d > 0.0f;
            acc[7] += (np_ && pos) ? 1.0f : 0.0f;
            acc[8] += pos ? 1.0f : 0.0f;
        }
    }
}

__global__ __launch_bounds__(256) void k1_kernel(
    const float* __restrict__ demand,
    const float* __restrict__ transit,
    const int* __restrict__ ntr,
    const unsigned char* __restrict__ hp_raw,
    const int* __restrict__ flag,
    float* __restrict__ ws)
{
    __shared__ float red[4][9];
    const int tid = threadIdx.x;
    const int wave = tid >> 6, lane = tid & 63;
    const int b = blockIdx.x >> 4, sub = blockIdx.x & 15;
    const size_t e0 = (size_t)b * NNE + (size_t)sub * (NNE / SUBS) + (size_t)tid * 4;

    float acc[9] = {0, 0, 0, 0, 0, 0, 0, 0, 0};
    if (*flag != 0)
        k1loop<true>(demand + e0, transit + e0, ntr + e0, hp_raw + e0, acc);
    else
        k1loop<false>(demand + e0, transit + e0, ntr + e0, ((const int*)hp_raw) + e0, acc);

#pragma unroll
    for (int o = 32; o > 0; o >>= 1)
#pragma unroll
        for (int v = 0; v < 9; ++v) acc[v] += __shfl_down(acc[v], o);
    if (lane == 0)
#pragma unroll
        for (int v = 0; v < 9; ++v) red[wave][v] = acc[v];
    __syncthreads();
    if (tid < 9)
        ws[K1OFF + (size_t)blockIdx.x * K1STRIDE + tid] =
            red[0][tid] + red[1][tid] + red[2][tid] + red[3][tid];
}

// ---------------- K2: drive max ----------------
__global__ __launch_bounds__(256) void k2_kernel(
    const float* __restrict__ drive, float* __restrict__ ws)
{
    __shared__ float red[4];
    const int tid = threadIdx.x;
    const int wave = tid >> 6, lane = tid & 63;
    const int b = blockIdx.x >> 4, sub = blockIdx.x & 15;
    const float* p = drive + (size_t)b * NNE + (size_t)sub * (NNE / SUBS) + (size_t)tid * 4;

    float m0 = 0, m1 = 0, m2 = 0, m3 = 0;
#pragma unroll 4
    for (int it = 0; it < IT; ++it) {
        const float4 v = *(const float4*)(p + it * 1024);
        m0 = fmaxf(m0, v.x); m1 = fmaxf(m1, v.y);
        m2 = fmaxf(m2, v.z); m3 = fmaxf(m3, v.w);
    }
    float m = fmaxf(fmaxf(m0, m1), fmaxf(m2, m3));
#pragma unroll
    for (int o = 32; o > 0; o >>= 1) m = fmaxf(m, __shfl_down(m, o));
    if (lane == 0) red[wave] = m;
    __syncthreads();
    if (tid == 0)
        ws[K2OFF + blockIdx.x] = fmaxf(fmaxf(red[0], red[1]), fmaxf(red[2], red[3]));
}

// ---------------- K3: riders (demand + rseq) ----------------
__global__ __launch_bounds__(256) void k3_kernel(
    const float* __restrict__ demand,
    const int* __restrict__ rseq,
    float* __restrict__ ws)
{
    __shared__ float bins[4][NR];
    const int tid = threadIdx.x;
    const int wave = tid >> 6;
    for (int i = tid; i < 4 * NR; i += 256) ((float*)bins)[i] = 0.0f;
    __syncthreads();

    const int b = blockIdx.x >> 4, sub = blockIdx.x & 15;
    const size_t e0 = (size_t)b * NNE + (size_t)sub * (NNE / SUBS) + (size_t)tid * 4;
    const float* pd = demand + e0;
    const int* pr = rseq + e0 * 4;

#pragma unroll 2
    for (int it = 0; it < IT; ++it) {
        const int o = it * 1024;
        const float4 dem = *(const float4*)(pd + o);
        const int4 r0 = *(const int4*)(pr + o * 4);
        const int4 r1 = *(const int4*)(pr + o * 4 + 4);
        const int4 r2 = *(const int4*)(pr + o * 4 + 8);
        const int4 r3 = *(const int4*)(pr + o * 4 + 12);
        const float dm[4] = {dem.x, dem.y, dem.z, dem.w};
        const int rs[16] = {r0.x, r0.y, r0.z, r0.w, r1.x, r1.y, r1.z, r1.w,
                            r2.x, r2.y, r2.z, r2.w, r3.x, r3.y, r3.z, r3.w};
#pragma unroll
        for (int e = 0; e < 4; ++e) {
            const float d = dm[e];
#pragma unroll
            for (int k = 0; k < 4; ++k) {
                const int id = rs[e * 4 + k];
                if ((unsigned)id < (unsigned)NR) atomicAdd(&bins[wave][id], d);
            }
        }
    }
    __syncthreads();
    if (tid < NR)
        ws[K3OFF + (size_t)blockIdx.x * K3STRIDE + tid] =
            bins[0][tid] + bins[1][tid] + bins[2][tid] + bins[3][tid];
}

// ---------------- route leg times ----------------
__global__ __launch_bounds__(64) void route_kernel(
    const int* __restrict__ routes,
    const float* __restrict__ drive,
    float* __restrict__ ws)
{
    const int b = blockIdx.x;
    const int r = threadIdx.x;
    float t = 0.0f, used = 0.0f, oob = 0.0f;
    if (r < NR) {
        const int* rt = routes + (b * NR + r) * NL;
        int v[NL];
        int len = 0;
#pragma unroll
        for (int l = 0; l < NL; ++l) { v[l] = rt[l]; len += (v[l] > -1) ? 1 : 0; }
        const float* D = drive + (size_t)b * NNE;
#pragma unroll
        for (int l = 0; l < NL - 1; ++l) {
            int f = v[l], to = v[l + 1];
            if (f >= 0 && to >= 0)
                t += D[f * NDIM + to] + D[to * NDIM + f] + 120.0f;
        }
        used = (len > 0) ? 1.0f : 0.0f;
        int delta = 2 - len;
        oob = (len > 0 && delta > 0) ? (float)delta : 0.0f;
    }
#pragma unroll
    for (int o = 32; o > 0; o >>= 1) {
        t += __shfl_down(t, o);
        used += __shfl_down(used, o);
        oob += __shfl_down(oob, o);
    }
    if (r == 0) {
        float* a = ws + RT_OFF + b * 4;
        a[0] = t; a[1] = used; a[2] = oob;
    }
}

// ---------------- finalize ----------------
__global__ __launch_bounds__(64) void final_kernel(const float* __restrict__ ws,
                                                   float* __restrict__ out) {
    __shared__ float fin[50];
    const int b = blockIdx.x;
    const int v = threadIdx.x;
    if (v < 9) {
        float a = 0.0f;
#pragma unroll
        for (int s = 0; s < SUBS; ++s)
            a += ws[K1OFF + (size_t)(b * SUBS + s) * K1STRIDE + v];
        fin[v] = a;
    } else if (v == 9) {
        float m = 0.0f;
#pragma unroll
        for (int s = 0; s < SUBS; ++s)
            m = fmaxf(m, ws[K2OFF + b * SUBS + s]);
        fin[9] = m;
    } else if (v < 50) {
        float a = 0.0f;
#pragma unroll
        for (int s = 0; s < SUBS; ++s)
            a += ws[K3OFF + (size_t)(b * SUBS + s) * K3STRIDE + (v - 10)];
        fin[v] = a;
    }
    __syncthreads();
    if (v == 0) {
        const float* rt = ws + RT_OFF + b * 4;
        const float trt = rt[0], nru = rt[1], noob = rt[2];
        const float dmdt = fin[4], uns = fin[5], tdem = fin[6];
        const float ndisc = fin[7], nedge = fin[8], tn = fin[9];
        const float served = tdem - uns;
        const float cost = 0.5f * ((dmdt / (served + 1e-6f)) / tn)
                         + 0.5f * (trt / (tn * nru + 1e-6f))
                         + 5.0f * (ndisc / nedge + noob / (nru * 2.0f + 1e-6f));
        out[b] = cost;
        out[64 + NB * NR + NB * 4 + b] = trt;
    }
    if (v < 4) out[64 + NB * NR + b * 4 + v] = fin[v];
    if (v >= 10 && v < 50) out[64 + b * NR + (v - 10)] = fin[v];
}

extern "C" void kernel_launch(void* const* d_in, const int* in_sizes, int n_in,
                              void* d_out, int out_size, void* d_ws, size_t ws_size,
                              hipStream_t stream) {
    const float* demand  = (const float*)d_in[0];
    const float* drive   = (const float*)d_in[1];
    const float* transit = (const float*)d_in[2];
    const unsigned char* hp = (const unsigned char*)d_in[3];
    const int* ntr    = (const int*)d_in[4];
    const int* routes = (const int*)d_in[5];
    const int* rseq   = (const int*)d_in[6];
    float* out = (float*)d_out;
    float* ws  = (float*)d_ws;
    int* flag  = (int*)(ws + FLAG_OFF);

    detect_kernel<<<1, 64, 0, stream>>>((const unsigned int*)hp, flag);
    route_kernel<<<NB, 64, 0, stream>>>(routes, drive, ws);
    k1_kernel<<<NB * SUBS, 256, 0, stream>>>(demand, transit, ntr, hp, flag, ws);
    k2_kernel<<<NB * SUBS, 256, 0, stream>>>(drive, ws);
    k3_kernel<<<NB * SUBS, 256, 0, stream>>>(demand, rseq, ws);
    final_kernel<<<NB, 64, 0, stream>>>(ws, out);
}

// Round 5
// 151.196 us; speedup vs baseline: 2.7105x; 2.7105x over previous
//
#include <hip/hip_runtime.h>

#define NB 64
#define NDIM 512
#define NNE (NDIM * NDIM)      // 262144
#define NR 40
#define NL 20
#define SUBS 16                // blocks per batch
#define IT 16                  // float4 iters per thread (64 elems)
#define BINS 41                // 40 real + 1 dummy for invalid ids

// ws layout (floats):
#define K1OFF 0
#define K1STRIDE 16
#define K2OFF (NB * SUBS * K1STRIDE)           // 16384
#define K3OFF (K2OFF + NB * SUBS)              // 17408
#define K3STRIDE 48
#define RT_OFF (K3OFF + NB * SUBS * K3STRIDE)  // 66560
#define FLAG_OFF (RT_OFF + NB * 4)             // 66816  (~261 KB total)

__global__ void detect_kernel(const unsigned int* __restrict__ hp, int* __restrict__ flag) {
    unsigned int v = hp[threadIdx.x];
    unsigned long long m = __ballot(v > 1u);
    if (threadIdx.x == 0) *flag = (m != 0ull) ? 1 : 0;
}

// ---------------- K1: demand+transit+ntr+has_path scalar sums ----------------
template<bool BYTE>
__device__ __forceinline__ void k1loop(const float* __restrict__ pd,
                                       const float* __restrict__ pt,
                                       const int* __restrict__ pn,
                                       const void* __restrict__ ph,
                                       float acc[9])
{
#pragma unroll 4
    for (int it = 0; it < IT; ++it) {
        const int o = it * 1024;
        const float4 dem = *(const float4*)(pd + o);
        const float4 tt  = *(const float4*)(pt + o);
        const int4   nt  = *(const int4*)(pn + o);
        int h[4];
        if (BYTE) {
            const uchar4 hb = *(const uchar4*)((const unsigned char*)ph + o);
            h[0] = hb.x; h[1] = hb.y; h[2] = hb.z; h[3] = hb.w;
        } else {
            const int4 hw = *(const int4*)((const int*)ph + o);
            h[0] = hw.x; h[1] = hw.y; h[2] = hw.z; h[3] = hw.w;
        }
        const float dm[4] = {dem.x, dem.y, dem.z, dem.w};
        const float tv[4] = {tt.x, tt.y, tt.z, tt.w};
        const int   nv[4] = {nt.x, nt.y, nt.z, nt.w};
#pragma unroll
        for (int e = 0; e < 4; ++e) {
            const float d = dm[e];
            const bool np_ = (h[e] == 0);
            const int nte = np_ ? 3 : nv[e];
            acc[0] += (nte == 0) ? d : 0.0f;
            acc[1] += (nte == 1) ? d : 0.0f;
            acc[2] += (nte == 2) ? d : 0.0f;
            acc[3] += (nte > 2) ? d : 0.0f;
            acc[4] += np_ ? 0.0f : d * tv[e];
            acc[5] += np_ ? d : 0.0f;
            acc[6] += d;
            const bool pos = d > 0.0f;
            acc[7] += (np_ && pos) ? 1.0f : 0.0f;
            acc[8] += pos ? 1.0f : 0.0f;
        }
    }
}

__global__ __launch_bounds__(256) void k1_kernel(
    const float* __restrict__ demand,
    const float* __restrict__ transit,
    const int* __restrict__ ntr,
    const unsigned char* __restrict__ hp_raw,
    const int* __restrict__ flag,
    float* __restrict__ ws)
{
    __shared__ float red[4][9];
    const int tid = threadIdx.x;
    const int wave = tid >> 6, lane = tid & 63;
    const int b = blockIdx.x >> 4, sub = blockIdx.x & 15;
    const size_t e0 = (size_t)b * NNE + (size_t)sub * (NNE / SUBS) + (size_t)tid * 4;

    float acc[9] = {0, 0, 0, 0, 0, 0, 0, 0, 0};
    if (*flag != 0)
        k1loop<true>(demand + e0, transit + e0, ntr + e0, hp_raw + e0, acc);
    else
        k1loop<false>(demand + e0, transit + e0, ntr + e0, ((const int*)hp_raw) + e0, acc);

#pragma unroll
    for (int o = 32; o > 0; o >>= 1)
#pragma unroll
        for (int v = 0; v < 9; ++v) acc[v] += __shfl_down(acc[v], o);
    if (lane == 0)
#pragma unroll
        for (int v = 0; v < 9; ++v) red[wave][v] = acc[v];
    __syncthreads();
    if (tid < 9)
        ws[K1OFF + (size_t)blockIdx.x * K1STRIDE + tid] =
            red[0][tid] + red[1][tid] + red[2][tid] + red[3][tid];
}

// ---------------- K2: drive max ----------------
__global__ __launch_bounds__(256) void k2_kernel(
    const float* __restrict__ drive, float* __restrict__ ws)
{
    __shared__ float red[4];
    const int tid = threadIdx.x;
    const int wave = tid >> 6, lane = tid & 63;
    const int b = blockIdx.x >> 4, sub = blockIdx.x & 15;
    const float* p = drive + (size_t)b * NNE + (size_t)sub * (NNE / SUBS) + (size_t)tid * 4;

    float m0 = 0, m1 = 0, m2 = 0, m3 = 0;
#pragma unroll 4
    for (int it = 0; it < IT; ++it) {
        const float4 v = *(const float4*)(p + it * 1024);
        m0 = fmaxf(m0, v.x); m1 = fmaxf(m1, v.y);
        m2 = fmaxf(m2, v.z); m3 = fmaxf(m3, v.w);
    }
    float m = fmaxf(fmaxf(m0, m1), fmaxf(m2, m3));
#pragma unroll
    for (int o = 32; o > 0; o >>= 1) m = fmaxf(m, __shfl_down(m, o));
    if (lane == 0) red[wave] = m;
    __syncthreads();
    if (tid == 0)
        ws[K2OFF + blockIdx.x] = fmaxf(fmaxf(red[0], red[1]), fmaxf(red[2], red[3]));
}

// ---------------- K3: riders (demand + rseq), private-row LDS, NO atomics ----
__global__ __launch_bounds__(256) void k3_kernel(
    const float* __restrict__ demand,
    const int* __restrict__ rseq,
    float* __restrict__ ws)
{
    __shared__ float bins[256 * BINS];   // 42 KB; one private row of 41 bins per thread
    const int tid = threadIdx.x;
    float* __restrict__ myrow = bins + tid * BINS;
#pragma unroll
    for (int i = 0; i < BINS; ++i) myrow[i] = 0.0f;   // private row: no barrier needed

    const int b = blockIdx.x >> 4, sub = blockIdx.x & 15;
    const size_t e0 = (size_t)b * NNE + (size_t)sub * (NNE / SUBS) + (size_t)tid * 4;
    const float* pd = demand + e0;
    const int* pr = rseq + e0 * 4;

#pragma unroll 2
    for (int it = 0; it < IT; ++it) {
        const int o = it * 1024;
        const float4 dem = *(const float4*)(pd + o);
        const int4 r0 = *(const int4*)(pr + o * 4);
        const int4 r1 = *(const int4*)(pr + o * 4 + 4);
        const int4 r2 = *(const int4*)(pr + o * 4 + 8);
        const int4 r3 = *(const int4*)(pr + o * 4 + 12);
        const float dm[4] = {dem.x, dem.y, dem.z, dem.w};
        const int rs[16] = {r0.x, r0.y, r0.z, r0.w, r1.x, r1.y, r1.z, r1.w,
                            r2.x, r2.y, r2.z, r2.w, r3.x, r3.y, r3.z, r3.w};
#pragma unroll
        for (int e = 0; e < 4; ++e) {
            const float d = dm[e];
#pragma unroll
            for (int k = 0; k < 4; ++k) {
                // -1 -> 0xFFFFFFFF -> min gives dummy bin 40; valid 0..39 unchanged
                const unsigned row = min((unsigned)rs[e * 4 + k], (unsigned)(BINS - 1));
                myrow[row] += d;   // ds_read + v_add + ds_write, same-lane private
            }
        }
    }
    __syncthreads();

    // reduce 256 rows x 40 bins
    if (tid < NR) {
        float s = 0.0f;
        for (int r = 0; r < 256; ++r) s += bins[r * BINS + tid];
        ws[K3OFF + (size_t)blockIdx.x * K3STRIDE + tid] = s;
    }
}

// ---------------- route leg times ----------------
__global__ __launch_bounds__(64) void route_kernel(
    const int* __restrict__ routes,
    const float* __restrict__ drive,
    float* __restrict__ ws)
{
    const int b = blockIdx.x;
    const int r = threadIdx.x;
    float t = 0.0f, used = 0.0f, oob = 0.0f;
    if (r < NR) {
        const int* rt = routes + (b * NR + r) * NL;
        int v[NL];
        int len = 0;
#pragma unroll
        for (int l = 0; l < NL; ++l) { v[l] = rt[l]; len += (v[l] > -1) ? 1 : 0; }
        const float* D = drive + (size_t)b * NNE;
#pragma unroll
        for (int l = 0; l < NL - 1; ++l) {
            int f = v[l], to = v[l + 1];
            if (f >= 0 && to >= 0)
                t += D[f * NDIM + to] + D[to * NDIM + f] + 120.0f;
        }
        used = (len > 0) ? 1.0f : 0.0f;
        int delta = 2 - len;
        oob = (len > 0 && delta > 0) ? (float)delta : 0.0f;
    }
#pragma unroll
    for (int o = 32; o > 0; o >>= 1) {
        t += __shfl_down(t, o);
        used += __shfl_down(used, o);
        oob += __shfl_down(oob, o);
    }
    if (r == 0) {
        float* a = ws + RT_OFF + b * 4;
        a[0] = t; a[1] = used; a[2] = oob;
    }
}

// ---------------- finalize ----------------
__global__ __launch_bounds__(64) void final_kernel(const float* __restrict__ ws,
                                                   float* __restrict__ out) {
    __shared__ float fin[50];
    const int b = blockIdx.x;
    const int v = threadIdx.x;
    if (v < 9) {
        float a = 0.0f;
#pragma unroll
        for (int s = 0; s < SUBS; ++s)
            a += ws[K1OFF + (size_t)(b * SUBS + s) * K1STRIDE + v];
        fin[v] = a;
    } else if (v == 9) {
        float m = 0.0f;
#pragma unroll
        for (int s = 0; s < SUBS; ++s)
            m = fmaxf(m, ws[K2OFF + b * SUBS + s]);
        fin[9] = m;
    } else if (v < 50) {
        float a = 0.0f;
#pragma unroll
        for (int s = 0; s < SUBS; ++s)
            a += ws[K3OFF + (size_t)(b * SUBS + s) * K3STRIDE + (v - 10)];
        fin[v] = a;
    }
    __syncthreads();
    if (v == 0) {
        const float* rt = ws + RT_OFF + b * 4;
        const float trt = rt[0], nru = rt[1], noob = rt[2];
        const float dmdt = fin[4], uns = fin[5], tdem = fin[6];
        const float ndisc = fin[7], nedge = fin[8], tn = fin[9];
        const float served = tdem - uns;
        const float cost = 0.5f * ((dmdt / (served + 1e-6f)) / tn)
                         + 0.5f * (trt / (tn * nru + 1e-6f))
                         + 5.0f * (ndisc / nedge + noob / (nru * 2.0f + 1e-6f));
        out[b] = cost;
        out[64 + NB * NR + NB * 4 + b] = trt;
    }
    if (v < 4) out[64 + NB * NR + b * 4 + v] = fin[v];
    if (v >= 10 && v < 50) out[64 + b * NR + (v - 10)] = fin[v];
}

extern "C" void kernel_launch(void* const* d_in, const int* in_sizes, int n_in,
                              void* d_out, int out_size, void* d_ws, size_t ws_size,
                              hipStream_t stream) {
    const float* demand  = (const float*)d_in[0];
    const float* drive   = (const float*)d_in[1];
    const float* transit = (const float*)d_in[2];
    const unsigned char* hp = (const unsigned char*)d_in[3];
    const int* ntr    = (const int*)d_in[4];
    const int* routes = (const int*)d_in[5];
    const int* rseq   = (const int*)d_in[6];
    float* out = (float*)d_out;
    float* ws  = (float*)d_ws;
    int* flag  = (int*)(ws + FLAG_OFF);

    detect_kernel<<<1, 64, 0, stream>>>((const unsigned int*)hp, flag);
    route_kernel<<<NB, 64, 0, stream>>>(routes, drive, ws);
    k1_kernel<<<NB * SUBS, 256, 0, stream>>>(demand, transit, ntr, hp, flag, ws);
    k2_kernel<<<NB * SUBS, 256, 0, stream>>>(drive, ws);
    k3_kernel<<<NB * SUBS, 256, 0, stream>>>(demand, rseq, ws);
    final_kernel<<<NB, 64, 0, stream>>>(ws, out);
}

// Round 6
// 137.849 us; speedup vs baseline: 2.9730x; 1.0968x over previous
//
#include <hip/hip_runtime.h>

#define NB 64
#define NDIM 512
#define NNE (NDIM * NDIM)      // 262144
#define NR 40
#define NL 20
#define SUBS 16                // blocks per batch
#define IT 16                  // float4 iters per thread (64 elems)
#define BINS 41                // 40 real + 1 dummy for invalid ids

// ws layout (floats):
//   per main block, MAIN_STRIDE floats:
//     [0..3]=tat, 4=dmd_time, 5=unserved, 6=tot_dem, 7=n_disc, 8=n_edges,
//     9=max_drive, [10..49]=riders
#define MAIN_STRIDE 64
#define RT_OFF (NB * SUBS * MAIN_STRIDE)       // 65536
#define FLAG_OFF (RT_OFF + NB * 4)             // 65792 (~263 KB)

__global__ void detect_kernel(const unsigned int* __restrict__ hp, int* __restrict__ flag) {
    unsigned int v = hp[threadIdx.x];
    unsigned long long m = __ballot(v > 1u);
    if (threadIdx.x == 0) *flag = (m != 0ull) ? 1 : 0;
}

// ---------------- fused main: K1 scalars + K2 max + K3 rider bins ----------------
template<bool BYTE>
__device__ __forceinline__ void mloop(
    const float* __restrict__ pd, const float* __restrict__ pt,
    const float* __restrict__ pdr, const int* __restrict__ pn,
    const void* __restrict__ ph, const int* __restrict__ pr,
    float acc[10], float* __restrict__ myrow)
{
#pragma unroll 2
    for (int it = 0; it < IT; ++it) {
        const int o = it * 1024;
        const float4 dem = *(const float4*)(pd + o);
        const float4 tt  = *(const float4*)(pt + o);
        const float4 dt  = *(const float4*)(pdr + o);
        const int4   nt  = *(const int4*)(pn + o);
        const int4 r0 = *(const int4*)(pr + o * 4);
        const int4 r1 = *(const int4*)(pr + o * 4 + 4);
        const int4 r2 = *(const int4*)(pr + o * 4 + 8);
        const int4 r3 = *(const int4*)(pr + o * 4 + 12);
        int h[4];
        if (BYTE) {
            const uchar4 hb = *(const uchar4*)((const unsigned char*)ph + o);
            h[0] = hb.x; h[1] = hb.y; h[2] = hb.z; h[3] = hb.w;
        } else {
            const int4 hw = *(const int4*)((const int*)ph + o);
            h[0] = hw.x; h[1] = hw.y; h[2] = hw.z; h[3] = hw.w;
        }
        const float dm[4] = {dem.x, dem.y, dem.z, dem.w};
        const float tv[4] = {tt.x, tt.y, tt.z, tt.w};
        const float dv[4] = {dt.x, dt.y, dt.z, dt.w};
        const int   nv[4] = {nt.x, nt.y, nt.z, nt.w};
        const int rs[16] = {r0.x, r0.y, r0.z, r0.w, r1.x, r1.y, r1.z, r1.w,
                            r2.x, r2.y, r2.z, r2.w, r3.x, r3.y, r3.z, r3.w};
#pragma unroll
        for (int e = 0; e < 4; ++e) {
            const float d = dm[e];
            const bool np_ = (h[e] == 0);
            const int nte = np_ ? 3 : nv[e];
            acc[0] += (nte == 0) ? d : 0.0f;
            acc[1] += (nte == 1) ? d : 0.0f;
            acc[2] += (nte == 2) ? d : 0.0f;
            acc[3] += (nte > 2) ? d : 0.0f;
            acc[4] += np_ ? 0.0f : d * tv[e];
            acc[5] += np_ ? d : 0.0f;
            acc[6] += d;
            const bool pos = d > 0.0f;
            acc[7] += (np_ && pos) ? 1.0f : 0.0f;
            acc[8] += pos ? 1.0f : 0.0f;
            acc[9] = fmaxf(acc[9], dv[e]);
#pragma unroll
            for (int k = 0; k < 4; ++k) {
                // -1 -> 0xFFFFFFFF -> min gives dummy bin 40; valid 0..39 unchanged
                const unsigned row = min((unsigned)rs[e * 4 + k], (unsigned)(BINS - 1));
                myrow[row] += d;   // private row: plain ds RMW, no atomics
            }
        }
    }
}

__global__ __launch_bounds__(256, 3) void main_kernel(
    const float* __restrict__ demand,
    const float* __restrict__ transit,
    const float* __restrict__ drive,
    const int* __restrict__ ntr,
    const unsigned char* __restrict__ hp_raw,
    const int* __restrict__ rseq,
    const int* __restrict__ flag,
    float* __restrict__ ws)
{
    __shared__ float bins[256 * BINS];   // 42 KB; one private 41-bin row per thread
    __shared__ float red[4][10];
    const int tid = threadIdx.x;
    const int wave = tid >> 6, lane = tid & 63;
    float* __restrict__ myrow = bins + tid * BINS;
#pragma unroll
    for (int i = 0; i < BINS; ++i) myrow[i] = 0.0f;   // private: no barrier needed

    const int b = blockIdx.x >> 4, sub = blockIdx.x & 15;
    const size_t e0 = (size_t)b * NNE + (size_t)sub * (NNE / SUBS) + (size_t)tid * 4;

    float acc[10] = {0, 0, 0, 0, 0, 0, 0, 0, 0, 0};
    if (*flag != 0)
        mloop<true>(demand + e0, transit + e0, drive + e0, ntr + e0,
                    hp_raw + e0, rseq + e0 * 4, acc, myrow);
    else
        mloop<false>(demand + e0, transit + e0, drive + e0, ntr + e0,
                     ((const int*)hp_raw) + e0, rseq + e0 * 4, acc, myrow);

    // wave reduction: 9 sums + 1 max
#pragma unroll
    for (int o = 32; o > 0; o >>= 1) {
#pragma unroll
        for (int v = 0; v < 9; ++v) acc[v] += __shfl_down(acc[v], o);
        acc[9] = fmaxf(acc[9], __shfl_down(acc[9], o));
    }
    if (lane == 0)
#pragma unroll
        for (int v = 0; v < 10; ++v) red[wave][v] = acc[v];
    __syncthreads();   // red + bins complete

    float* part = ws + (size_t)blockIdx.x * MAIN_STRIDE;
    if (tid < 10) {
        if (tid == 9)
            part[9] = fmaxf(fmaxf(red[0][9], red[1][9]), fmaxf(red[2][9], red[3][9]));
        else
            part[tid] = red[0][tid] + red[1][tid] + red[2][tid] + red[3][tid];
    }
    if (tid < NR) {
        float s = 0.0f;
        for (int r = 0; r < 256; ++r) s += bins[r * BINS + tid];
        part[10 + tid] = s;
    }
}

// ---------------- route leg times ----------------
__global__ __launch_bounds__(64) void route_kernel(
    const int* __restrict__ routes,
    const float* __restrict__ drive,
    float* __restrict__ ws)
{
    const int b = blockIdx.x;
    const int r = threadIdx.x;
    float t = 0.0f, used = 0.0f, oob = 0.0f;
    if (r < NR) {
        const int* rt = routes + (b * NR + r) * NL;
        int v[NL];
        int len = 0;
#pragma unroll
        for (int l = 0; l < NL; ++l) { v[l] = rt[l]; len += (v[l] > -1) ? 1 : 0; }
        const float* D = drive + (size_t)b * NNE;
#pragma unroll
        for (int l = 0; l < NL - 1; ++l) {
            int f = v[l], to = v[l + 1];
            if (f >= 0 && to >= 0)
                t += D[f * NDIM + to] + D[to * NDIM + f] + 120.0f;
        }
        used = (len > 0) ? 1.0f : 0.0f;
        int delta = 2 - len;
        oob = (len > 0 && delta > 0) ? (float)delta : 0.0f;
    }
#pragma unroll
    for (int o = 32; o > 0; o >>= 1) {
        t += __shfl_down(t, o);
        used += __shfl_down(used, o);
        oob += __shfl_down(oob, o);
    }
    if (r == 0) {
        float* a = ws + RT_OFF + b * 4;
        a[0] = t; a[1] = used; a[2] = oob;
    }
}

// ---------------- finalize ----------------
__global__ __launch_bounds__(64) void final_kernel(const float* __restrict__ ws,
                                                   float* __restrict__ out) {
    __shared__ float fin[50];
    const int b = blockIdx.x;
    const int v = threadIdx.x;
    if (v < 50) {
        const float* p = ws + (size_t)b * SUBS * MAIN_STRIDE + v;
        float a = p[0];
#pragma unroll
        for (int s = 1; s < SUBS; ++s) {
            const float x = p[(size_t)s * MAIN_STRIDE];
            a = (v == 9) ? fmaxf(a, x) : (a + x);
        }
        fin[v] = a;
    }
    __syncthreads();
    if (v == 0) {
        const float* rt = ws + RT_OFF + b * 4;
        const float trt = rt[0], nru = rt[1], noob = rt[2];
        const float dmdt = fin[4], uns = fin[5], tdem = fin[6];
        const float ndisc = fin[7], nedge = fin[8], tn = fin[9];
        const float served = tdem - uns;
        const float cost = 0.5f * ((dmdt / (served + 1e-6f)) / tn)
                         + 0.5f * (trt / (tn * nru + 1e-6f))
                         + 5.0f * (ndisc / nedge + noob / (nru * 2.0f + 1e-6f));
        out[b] = cost;
        out[64 + NB * NR + NB * 4 + b] = trt;
    }
    if (v < 4) out[64 + NB * NR + b * 4 + v] = fin[v];
    if (v >= 10 && v < 50) out[64 + b * NR + (v - 10)] = fin[v];
}

extern "C" void kernel_launch(void* const* d_in, const int* in_sizes, int n_in,
                              void* d_out, int out_size, void* d_ws, size_t ws_size,
                              hipStream_t stream) {
    const float* demand  = (const float*)d_in[0];
    const float* drive   = (const float*)d_in[1];
    const float* transit = (const float*)d_in[2];
    const unsigned char* hp = (const unsigned char*)d_in[3];
    const int* ntr    = (const int*)d_in[4];
    const int* routes = (const int*)d_in[5];
    const int* rseq   = (const int*)d_in[6];
    float* out = (float*)d_out;
    float* ws  = (float*)d_ws;
    int* flag  = (int*)(ws + FLAG_OFF);

    detect_kernel<<<1, 64, 0, stream>>>((const unsigned int*)hp, flag);
    route_kernel<<<NB, 64, 0, stream>>>(routes, drive, ws);
    main_kernel<<<NB * SUBS, 256, 0, stream>>>(demand, transit, drive, ntr, hp, rseq, flag, ws);
    final_kernel<<<NB, 64, 0, stream>>>(ws, out);
}

// Round 7
// 133.807 us; speedup vs baseline: 3.0628x; 1.0302x over previous
//
#include <hip/hip_runtime.h>

#define NB 64
#define NDIM 512
#define NNE (NDIM * NDIM)      // 262144
#define NR 40
#define NL 20
#define SUBS 16                // blocks per batch
#define IT 16                  // float4 iters per thread (64 elems)
#define BINS 41                // 40 real + 1 dummy for invalid ids

// ws layout (floats):
//   per main block, MAIN_STRIDE floats:
//     [0..3]=tat, 4=dmd_time, 5=unserved, 6=tot_dem, 7=n_disc, 8=n_edges,
//     9=max_drive, [10..49]=riders
#define MAIN_STRIDE 64
#define RT_OFF (NB * SUBS * MAIN_STRIDE)       // 65536
#define FLAG_OFF (RT_OFF + NB * 4)             // 65792 (~263 KB)

__global__ void detect_kernel(const unsigned int* __restrict__ hp, int* __restrict__ flag) {
    unsigned int v = hp[threadIdx.x];
    unsigned long long m = __ballot(v > 1u);
    if (threadIdx.x == 0) *flag = (m != 0ull) ? 1 : 0;
}

// ---------------- fused main: scalars + max + rider bins (batched LDS RMW) ----
template<bool BYTE>
__device__ __forceinline__ void mloop(
    const float* __restrict__ pd, const float* __restrict__ pt,
    const float* __restrict__ pdr, const int* __restrict__ pn,
    const void* __restrict__ ph, const int* __restrict__ pr,
    float acc[10], float* __restrict__ myrow)
{
#pragma unroll 2
    for (int it = 0; it < IT; ++it) {
        const int o = it * 1024;
        const float4 dem = *(const float4*)(pd + o);
        const float4 tt  = *(const float4*)(pt + o);
        const float4 dt  = *(const float4*)(pdr + o);
        const int4   nt  = *(const int4*)(pn + o);
        const int4 r0 = *(const int4*)(pr + o * 4);
        const int4 r1 = *(const int4*)(pr + o * 4 + 4);
        const int4 r2 = *(const int4*)(pr + o * 4 + 8);
        const int4 r3 = *(const int4*)(pr + o * 4 + 12);
        int h[4];
        if (BYTE) {
            const uchar4 hb = *(const uchar4*)((const unsigned char*)ph + o);
            h[0] = hb.x; h[1] = hb.y; h[2] = hb.z; h[3] = hb.w;
        } else {
            const int4 hw = *(const int4*)((const int*)ph + o);
            h[0] = hw.x; h[1] = hw.y; h[2] = hw.z; h[3] = hw.w;
        }
        const float dm[4] = {dem.x, dem.y, dem.z, dem.w};
        const float tv[4] = {tt.x, tt.y, tt.z, tt.w};
        const float dv[4] = {dt.x, dt.y, dt.z, dt.w};
        const int   nv[4] = {nt.x, nt.y, nt.z, nt.w};
        const int4  rr[4] = {r0, r1, r2, r3};
#pragma unroll
        for (int e = 0; e < 4; ++e) {
            const float d = dm[e];
            const bool np_ = (h[e] == 0);
            const int nte = np_ ? 3 : nv[e];
            acc[0] += (nte == 0) ? d : 0.0f;
            acc[1] += (nte == 1) ? d : 0.0f;
            acc[2] += (nte == 2) ? d : 0.0f;
            acc[3] += (nte > 2) ? d : 0.0f;
            acc[4] += np_ ? 0.0f : d * tv[e];
            acc[5] += np_ ? d : 0.0f;
            acc[6] += d;
            const bool pos = d > 0.0f;
            acc[7] += (np_ && pos) ? 1.0f : 0.0f;
            acc[8] += pos ? 1.0f : 0.0f;
            acc[9] = fmaxf(acc[9], dv[e]);

            // ---- batched rider RMW: 4 reads, dup-resolve in regs, 4 writes ----
            // invalid (-1) -> 0xFFFFFFFF -> min -> dummy bin 40
            const unsigned b0 = min((unsigned)rr[e].x, (unsigned)(BINS - 1));
            const unsigned b1 = min((unsigned)rr[e].y, (unsigned)(BINS - 1));
            const unsigned b2 = min((unsigned)rr[e].z, (unsigned)(BINS - 1));
            const unsigned b3 = min((unsigned)rr[e].w, (unsigned)(BINS - 1));
            // addend_k = d * (1 + #{j<k : bj == bk}); writes are in program
            // order, so the last duplicate (carrying the full sum) wins.
            const float a0 = d;
            const float a1 = d * (1.0f + (b1 == b0));
            const float a2 = d * (1.0f + (b2 == b0) + (b2 == b1));
            const float a3 = d * (1.0f + (b3 == b0) + (b3 == b1) + (b3 == b2));
            const float v0 = myrow[b0];
            const float v1 = myrow[b1];
            const float v2 = myrow[b2];
            const float v3 = myrow[b3];
            myrow[b0] = v0 + a0;
            myrow[b1] = v1 + a1;
            myrow[b2] = v2 + a2;
            myrow[b3] = v3 + a3;
        }
    }
}

__global__ __launch_bounds__(256, 3) void main_kernel(
    const float* __restrict__ demand,
    const float* __restrict__ transit,
    const float* __restrict__ drive,
    const int* __restrict__ ntr,
    const unsigned char* __restrict__ hp_raw,
    const int* __restrict__ rseq,
    const int* __restrict__ flag,
    float* __restrict__ ws)
{
    __shared__ float bins[256 * BINS];   // 42 KB; one private 41-bin row per thread
    __shared__ float red[4][10];
    __shared__ float red2[4][NR];
    const int tid = threadIdx.x;
    const int wave = tid >> 6, lane = tid & 63;
    float* __restrict__ myrow = bins + tid * BINS;
#pragma unroll
    for (int i = 0; i < BINS; ++i) myrow[i] = 0.0f;   // private: no barrier needed

    const int b = blockIdx.x >> 4, sub = blockIdx.x & 15;
    const size_t e0 = (size_t)b * NNE + (size_t)sub * (NNE / SUBS) + (size_t)tid * 4;

    float acc[10] = {0, 0, 0, 0, 0, 0, 0, 0, 0, 0};
    if (*flag != 0)
        mloop<true>(demand + e0, transit + e0, drive + e0, ntr + e0,
                    hp_raw + e0, rseq + e0 * 4, acc, myrow);
    else
        mloop<false>(demand + e0, transit + e0, drive + e0, ntr + e0,
                     ((const int*)hp_raw) + e0, rseq + e0 * 4, acc, myrow);

    // wave reduction: 9 sums + 1 max
#pragma unroll
    for (int o = 32; o > 0; o >>= 1) {
#pragma unroll
        for (int v = 0; v < 9; ++v) acc[v] += __shfl_down(acc[v], o);
        acc[9] = fmaxf(acc[9], __shfl_down(acc[9], o));
    }
    if (lane == 0)
#pragma unroll
        for (int v = 0; v < 10; ++v) red[wave][v] = acc[v];
    __syncthreads();   // red + bins complete

    float* part = ws + (size_t)blockIdx.x * MAIN_STRIDE;
    if (tid < 10) {
        if (tid == 9)
            part[9] = fmaxf(fmaxf(red[0][9], red[1][9]), fmaxf(red[2][9], red[3][9]));
        else
            part[tid] = red[0][tid] + red[1][tid] + red[2][tid] + red[3][tid];
    }

    // 4-way parallel tail reduction: 160 threads, each sums 64 rows of one bin
    if (tid < 4 * NR) {
        const int g = tid / NR, j = tid - g * NR;
        float s = 0.0f;
#pragma unroll 8
        for (int r = g * 64; r < g * 64 + 64; ++r) s += bins[r * BINS + j];
        red2[g][j] = s;
    }
    __syncthreads();
    if (tid < NR)
        part[10 + tid] = red2[0][tid] + red2[1][tid] + red2[2][tid] + red2[3][tid];
}

// ---------------- route leg times ----------------
__global__ __launch_bounds__(64) void route_kernel(
    const int* __restrict__ routes,
    const float* __restrict__ drive,
    float* __restrict__ ws)
{
    const int b = blockIdx.x;
    const int r = threadIdx.x;
    float t = 0.0f, used = 0.0f, oob = 0.0f;
    if (r < NR) {
        const int* rt = routes + (b * NR + r) * NL;
        int v[NL];
        int len = 0;
#pragma unroll
        for (int l = 0; l < NL; ++l) { v[l] = rt[l]; len += (v[l] > -1) ? 1 : 0; }
        const float* D = drive + (size_t)b * NNE;
#pragma unroll
        for (int l = 0; l < NL - 1; ++l) {
            int f = v[l], to = v[l + 1];
            if (f >= 0 && to >= 0)
                t += D[f * NDIM + to] + D[to * NDIM + f] + 120.0f;
        }
        used = (len > 0) ? 1.0f : 0.0f;
        int delta = 2 - len;
        oob = (len > 0 && delta > 0) ? (float)delta : 0.0f;
    }
#pragma unroll
    for (int o = 32; o > 0; o >>= 1) {
        t += __shfl_down(t, o);
        used += __shfl_down(used, o);
        oob += __shfl_down(oob, o);
    }
    if (r == 0) {
        float* a = ws + RT_OFF + b * 4;
        a[0] = t; a[1] = used; a[2] = oob;
    }
}

// ---------------- finalize ----------------
__global__ __launch_bounds__(64) void final_kernel(const float* __restrict__ ws,
                                                   float* __restrict__ out) {
    __shared__ float fin[50];
    const int b = blockIdx.x;
    const int v = threadIdx.x;
    if (v < 50) {
        const float* p = ws + (size_t)b * SUBS * MAIN_STRIDE + v;
        float a = p[0];
#pragma unroll
        for (int s = 1; s < SUBS; ++s) {
            const float x = p[(size_t)s * MAIN_STRIDE];
            a = (v == 9) ? fmaxf(a, x) : (a + x);
        }
        fin[v] = a;
    }
    __syncthreads();
    if (v == 0) {
        const float* rt = ws + RT_OFF + b * 4;
        const float trt = rt[0], nru = rt[1], noob = rt[2];
        const float dmdt = fin[4], uns = fin[5], tdem = fin[6];
        const float ndisc = fin[7], nedge = fin[8], tn = fin[9];
        const float served = tdem - uns;
        const float cost = 0.5f * ((dmdt / (served + 1e-6f)) / tn)
                         + 0.5f * (trt / (tn * nru + 1e-6f))
                         + 5.0f * (ndisc / nedge + noob / (nru * 2.0f + 1e-6f));
        out[b] = cost;
        out[64 + NB * NR + NB * 4 + b] = trt;
    }
    if (v < 4) out[64 + NB * NR + b * 4 + v] = fin[v];
    if (v >= 10 && v < 50) out[64 + b * NR + (v - 10)] = fin[v];
}

extern "C" void kernel_launch(void* const* d_in, const int* in_sizes, int n_in,
                              void* d_out, int out_size, void* d_ws, size_t ws_size,
                              hipStream_t stream) {
    const float* demand  = (const float*)d_in[0];
    const float* drive   = (const float*)d_in[1];
    const float* transit = (const float*)d_in[2];
    const unsigned char* hp = (const unsigned char*)d_in[3];
    const int* ntr    = (const int*)d_in[4];
    const int* routes = (const int*)d_in[5];
    const int* rseq   = (const int*)d_in[6];
    float* out = (float*)d_out;
    float* ws  = (float*)d_ws;
    int* flag  = (int*)(ws + FLAG_OFF);

    detect_kernel<<<1, 64, 0, stream>>>((const unsigned int*)hp, flag);
    route_kernel<<<NB, 64, 0, stream>>>(routes, drive, ws);
    main_kernel<<<NB * SUBS, 256, 0, stream>>>(demand, transit, drive, ntr, hp, rseq, flag, ws);
    final_kernel<<<NB, 64, 0, stream>>>(ws, out);
}